// Round 9
// baseline (1513.908 us; speedup 1.0000x reference)
//
#include <hip/hip_runtime.h>

// ---------------------------------------------------------------------------
// 2-layer GRU, H=256, seq=64, rows = B*N = 2048.
// 128 row-groups (16 rows) x 4 dim-slices (64 dims) = 512 WGs, grid 512,
// 2 blocks/CU (LDS 20.5 KB, __launch_bounds__(256,2)) -> one group's MALL
// waits overlap the co-resident group's compute.
// SPLIT-FLAG protocol: h0(t) emitted + flag0'd right after the L0 epilogue;
// layer-1 (gi1/gh1) runs AFTER the publish, gated by flag1 which lags a full
// phase -> inter-group critical chain is only {poll, stage, 24 MFMA, emit}.
// wh0 + wi0 B-fragments live in REGISTERS (loaded once) -> L0 chain has no
// L2 traffic; wi1/wh1 stream from L2 in the slack. h rings are MALL-coherent
// (relaxed agent-scope atomics); members of a group have consecutive bids ->
// deadlock-free under any dispatch/residency (groups are independent).
// ---------------------------------------------------------------------------

typedef __attribute__((ext_vector_type(8))) __bf16 bf8;
typedef __attribute__((ext_vector_type(8))) unsigned short u16x8;
typedef __attribute__((ext_vector_type(4))) float f32x4;

#define MFMA16(A, B, C) __builtin_amdgcn_mfma_f32_16x16x32_bf16((A), (B), (C), 0, 0, 0)

#define ROWS 2048
#define HID 256
#define NW 768
#define SLOT (ROWS * HID)                       // 524288
#define OUT_HID_OFF ((size_t)64 * ROWS * HID)   // 33554432
#define RSLOT 524288                            // u16 per ring slot: 128 g * 4096

static __device__ __forceinline__ float b2f(unsigned short u) {
  union { unsigned u32; float f; } v;
  v.u32 = ((unsigned)u) << 16;
  return v.f;
}
static __device__ __forceinline__ unsigned short f2b(float f) {
  unsigned u = __float_as_uint(f);
  u += 0x7fffu + ((u >> 16) & 1u);  // RNE
  return (unsigned short)(u >> 16);
}
static __device__ __forceinline__ float sigm(float x) {
  return 1.0f / (1.0f + __expf(-x));
}
static __device__ __forceinline__ float tanh_fast(float x) {
  x = fminf(15.0f, fmaxf(-15.0f, x));
  float e = __expf(2.0f * x);
  return (e - 1.0f) / (e + 1.0f);
}
static __device__ __forceinline__ float ldin(const void* p, int i, int f32w) {
  return f32w ? ((const float*)p)[i] : b2f(((const unsigned short*)p)[i]);
}
static __device__ __forceinline__ void stout(void* p, size_t i, float v, int f32w) {
  if (f32w) ((float*)p)[i] = v;
  else ((unsigned short*)p)[i] = f2b(v);
}

// Coherent 16B load / store: relaxed agent-scope u64 atomic pairs (bypass
// stale L1/L2; served at the MALL coherence point). Compiler-tracked vmcnt.
static __device__ __forceinline__ u16x8 ld_h16(const unsigned short* p) {
  union { unsigned long long q[2]; u16x8 b; } u;
  u.q[0] = __hip_atomic_load((const unsigned long long*)p, __ATOMIC_RELAXED,
                             __HIP_MEMORY_SCOPE_AGENT);
  u.q[1] = __hip_atomic_load((const unsigned long long*)(p + 4), __ATOMIC_RELAXED,
                             __HIP_MEMORY_SCOPE_AGENT);
  return u.b;
}
static __device__ __forceinline__ void st_h16(unsigned short* p, u16x8 v) {
  union { u16x8 s; unsigned long long q[2]; } u;
  u.s = v;
  __hip_atomic_store((unsigned long long*)p, u.q[0], __ATOMIC_RELAXED,
                     __HIP_MEMORY_SCOPE_AGENT);
  __hip_atomic_store((unsigned long long*)(p + 4), u.q[1], __ATOMIC_RELAXED,
                     __HIP_MEMORY_SCOPE_AGENT);
}

// --------------------------- dtype probe -----------------------------------
__global__ void probe_dtype(const unsigned short* x, unsigned* flag) {
  if (blockIdx.x != 0 || threadIdx.x != 0) return;
  int cnt = 0;
  for (int i = 0; i < 256; ++i) {
    float v = b2f(x[i]);
    if (v == v && fabsf(v) <= 8.0f) cnt++;
  }
  *flag = (cnt >= 250) ? 0u : 1u;  // 0 = bf16 world, 1 = f32 world
}

// --------------------------- weight pre-pack -------------------------------
// packed[nb][kk][lane][e] = W[kk*32 + (lane>>4)*8 + e][nb*16 + (lane&15)]
__global__ void pack_w(const void* __restrict__ W,
                       unsigned short* __restrict__ P, int KK,
                       const unsigned* __restrict__ flag) {
  int i = blockIdx.x * blockDim.x + threadIdx.x;
  int total = 48 * KK * 64;
  if (i >= total) return;
  int f32w = (int)*flag;
  int l = i & 63;
  int kk = (i >> 6) % KK;
  int nb = i / (64 * KK);
  int n = nb * 16 + (l & 15);
  int k0 = kk * 32 + (l >> 4) * 8;
  u16x8 tmp;
#pragma unroll
  for (int e = 0; e < 8; ++e) tmp[e] = f2b(ldin(W, (k0 + e) * NW + n, f32w));
  *(u16x8*)(P + (size_t)i * 8) = tmp;
}

// --------------------------- main kernel -----------------------------------
__global__ void __launch_bounds__(256, 2) gru_main(
    const void* __restrict__ x,
    const void* __restrict__ bi0, const void* __restrict__ bh0,
    const void* __restrict__ bi1, const void* __restrict__ bh1,
    const unsigned short* __restrict__ pwi0, const unsigned short* __restrict__ pwh0,
    const unsigned short* __restrict__ pwi1, const unsigned short* __restrict__ pwh1,
    void* __restrict__ out,
    unsigned short* __restrict__ ring0, unsigned short* __restrict__ ring1,
    unsigned* __restrict__ flags, const unsigned* __restrict__ flag) {
  __shared__ __align__(16) unsigned short AS[8192];    // 16 KB: [2][8][512]
  __shared__ __align__(16) unsigned short HS[2][1152]; // [2][16 rows][72]

  const int f32w = (int)*flag;
  const int tid = threadIdx.x;
  const int lane = tid & 63;
  const int wid = tid >> 6;
  const int bid = blockIdx.x;
  const int g = bid >> 2;      // 128 row groups of 16 rows (members adjacent)
  const int slice = bid & 3;   // dim slice (64 dims)
  const int nb = slice * 4 + wid;          // wave's 16-col block (0..15)

  const int d = nb * 16 + (lane & 15);
  const int rb = g * 16;
  const int arow = rb + (lane & 15);
  const int koff = (lane >> 4) * 8;
  const int rl = (lane >> 4) * 4;

  unsigned* flag0p = flags + (size_t)g * 64;
  unsigned* flag1p = flag0p + 32;

  const unsigned short* xw  = pwi0 + (size_t)nb * 1024;
  const unsigned short* w0  = pwh0 + (size_t)nb * 4096;
  const unsigned short* w1i = pwi1 + (size_t)nb * 4096;
  const unsigned short* w1h = pwh1 + (size_t)nb * 4096;

  // ---- register-resident wh0 (96 VGPR) + wi0 (24 VGPR) B-fragments ----
  bf8 w0r[3][8];
#pragma unroll
  for (int gate = 0; gate < 3; ++gate)
#pragma unroll
    for (int kk = 0; kk < 8; ++kk)
      w0r[gate][kk] = *(const bf8*)(w0 + gate * 65536 + kk * 512 + lane * 8);
  bf8 wxr[3][2];
#pragma unroll
  for (int gate = 0; gate < 3; ++gate)
#pragma unroll
    for (int kk = 0; kk < 2; ++kk)
      wxr[gate][kk] = *(const bf8*)(xw + gate * 16384 + kk * 512 + lane * 8);

  const float iR0 = ldin(bi0, d, f32w) + ldin(bh0, d, f32w);
  const float iZ0 = ldin(bi0, 256 + d, f32w) + ldin(bh0, 256 + d, f32w);
  const float iI0 = ldin(bi0, 512 + d, f32w);
  const float iH0 = ldin(bh0, 512 + d, f32w);
  const float iR1 = ldin(bi1, d, f32w) + ldin(bh1, d, f32w);
  const float iZ1 = ldin(bi1, 256 + d, f32w) + ldin(bh1, 256 + d, f32w);
  const float iI1 = ldin(bi1, 512 + d, f32w);
  const float iH1 = ldin(bh1, 512 + d, f32w);

  float h0p[4] = {0, 0, 0, 0};
  float h1p[4] = {0, 0, 0, 0};

  // emit constants (tid < 128: one 16B coherent store per layer)
  const int ekk = (tid >> 6) & 1;
  const int eln = tid & 63;
  const int ehs = (eln & 15) * 72 + ekk * 32 + (eln >> 4) * 8;
  const size_t ero = (size_t)g * 4096 + (size_t)(slice * 2 + ekk) * 512 + eln * 8;

  for (int t = 0; t <= 64; ++t) {
    const int sc = t & 1;
    const int sp = sc ^ 1;

    f32x4 aR0 = {iR0, iR0, iR0, iR0}, aZ0 = {iZ0, iZ0, iZ0, iZ0};
    f32x4 aI0 = {iI0, iI0, iI0, iI0}, aH0 = {iH0, iH0, iH0, iH0};
    f32x4 aR1 = {iR1, iR1, iR1, iR1}, aZ1 = {iZ1, iZ1, iZ1, iZ1};
    f32x4 aI1 = {iI1, iI1, iI1, iI1}, aH1 = {iH1, iH1, iH1, iH1};

    // ---- x-GEMM prefetch (register weights, no group dependency) ----
    if (t < 64) {
      size_t xoff = ((size_t)t * ROWS + arow) * 64 + koff;
#pragma unroll
      for (int kk = 0; kk < 2; ++kk) {
        union { u16x8 u; bf8 b; } A0;
        if (f32w) {
          const float* ab = (const float*)x + xoff;
#pragma unroll
          for (int e = 0; e < 8; ++e) A0.u[e] = f2b(ab[kk * 32 + e]);
        } else {
          A0.u = *(const u16x8*)((const unsigned short*)x + xoff + kk * 32);
        }
        aR0 = MFMA16(A0.b, wxr[0][kk], aR0);
        aZ0 = MFMA16(A0.b, wxr[1][kk], aZ0);
        aI0 = MFMA16(A0.b, wxr[2][kk], aI0);
      }
    }

    // ---- polls: flag1 (lagged, usually ready) then flag0 ----
    if (tid == 0) {
      if (t >= 2) {
        const unsigned tgt = 4u * (unsigned)(t - 1);
        while (__hip_atomic_load(flag1p, __ATOMIC_RELAXED,
                                 __HIP_MEMORY_SCOPE_AGENT) < tgt)
          __builtin_amdgcn_s_sleep(1);
      }
      if (t >= 1) {
        const unsigned tgt = 4u * (unsigned)t;
        while (__hip_atomic_load(flag0p, __ATOMIC_RELAXED,
                                 __HIP_MEMORY_SCOPE_AGENT) < tgt)
          __builtin_amdgcn_s_sleep(1);
      }
    }
    __syncthreads();

    // ---- stage h0(t-1) / h1(t-2) A-frags into LDS (coalesced, once/WG) ----
    if (t >= 1) {
      const unsigned short* r0 = ring0 + (size_t)sp * RSLOT + (size_t)g * 4096;
#pragma unroll
      for (int i = 0; i < 2; ++i) {
        int idx = tid + i * 256;
        int ff = idx >> 6, ln2 = idx & 63;
        *(u16x8*)(AS + ff * 512 + ln2 * 8) = ld_h16(r0 + ff * 512 + ln2 * 8);
      }
    }
    if (t >= 2) {
      const unsigned short* r1 = ring1 + (size_t)sc * RSLOT + (size_t)g * 4096;
#pragma unroll
      for (int i = 0; i < 2; ++i) {
        int idx = tid + i * 256;
        int ff = idx >> 6, ln2 = idx & 63;
        *(u16x8*)(AS + 4096 + ff * 512 + ln2 * 8) =
            ld_h16(r1 + ff * 512 + ln2 * 8);
      }
    }
    __syncthreads();

    // ---- L0: h0(t-1) @ wh0 (register B-frags) + epilogue ----
    if (t < 64) {
      if (t >= 1) {
#pragma unroll
        for (int kk = 0; kk < 8; ++kk) {
          bf8 A = *(const bf8*)(AS + kk * 512 + lane * 8);
          aR0 = MFMA16(A, w0r[0][kk], aR0);
          aZ0 = MFMA16(A, w0r[1][kk], aZ0);
          aH0 = MFMA16(A, w0r[2][kk], aH0);
        }
      }
#pragma unroll
      for (int j = 0; j < 4; ++j) {
        float r = sigm(aR0[j]);
        float z = sigm(aZ0[j]);
        float n = tanh_fast(aI0[j] + r * aH0[j]);
        float hv = (1.0f - z) * n + z * h0p[j];
        h0p[j] = hv;
        HS[0][(rl + j) * 72 + wid * 16 + (lane & 15)] = f2b(hv);
      }
    }
    __syncthreads();

    // ---- PUBLISH h0(t) EARLY: emit + flag0 before any layer-1 work ----
    if (t < 64 && tid < 128)
      st_h16(ring0 + (size_t)sc * RSLOT + ero, *(const u16x8*)(&HS[0][ehs]));
    asm volatile("s_waitcnt vmcnt(0)" ::: "memory");
    if (t < 64 && tid == 0)
      __hip_atomic_fetch_add(flag0p, 1u, __ATOMIC_RELAXED,
                             __HIP_MEMORY_SCOPE_AGENT);

    // ---- L1 (t-1): gi1 = h0(t-1)@wi1, gh1 = h1(t-2)@wh1 (L2-streamed B) ----
    if (t >= 1) {
#pragma unroll
      for (int kk = 0; kk < 8; ++kk) {
        const int lb = lane * 8;
        bf8 A0 = *(const bf8*)(AS + kk * 512 + lb);
        bf8 Br1 = *(const bf8*)(w1i + 0 * 65536 + kk * 512 + lb);
        bf8 Bz1 = *(const bf8*)(w1i + 1 * 65536 + kk * 512 + lb);
        bf8 Bn1 = *(const bf8*)(w1i + 2 * 65536 + kk * 512 + lb);
        aR1 = MFMA16(A0, Br1, aR1);
        aZ1 = MFMA16(A0, Bz1, aZ1);
        aI1 = MFMA16(A0, Bn1, aI1);
        if (t >= 2) {
          bf8 A1 = *(const bf8*)(AS + 4096 + kk * 512 + lb);
          bf8 Br = *(const bf8*)(w1h + 0 * 65536 + kk * 512 + lb);
          bf8 Bz = *(const bf8*)(w1h + 1 * 65536 + kk * 512 + lb);
          bf8 Bn = *(const bf8*)(w1h + 2 * 65536 + kk * 512 + lb);
          aR1 = MFMA16(A1, Br, aR1);
          aZ1 = MFMA16(A1, Bz, aZ1);
          aH1 = MFMA16(A1, Bn, aH1);
        }
      }
#pragma unroll
      for (int j = 0; j < 4; ++j) {
        float r = sigm(aR1[j]);
        float z = sigm(aZ1[j]);
        float n = tanh_fast(aI1[j] + r * aH1[j]);
        float hv = (1.0f - z) * n + z * h1p[j];
        h1p[j] = hv;
        HS[1][(rl + j) * 72 + wid * 16 + (lane & 15)] = f2b(hv);
      }
    }
    __syncthreads();  // HS[1] ready; also guards AS reuse next phase

    if (t >= 1 && t < 64 && tid < 128)
      st_h16(ring1 + (size_t)sp * RSLOT + ero, *(const u16x8*)(&HS[1][ehs]));
    asm volatile("s_waitcnt vmcnt(0)" ::: "memory");
    if (t >= 1 && t < 64 && tid == 0)
      __hip_atomic_fetch_add(flag1p, 1u, __ATOMIC_RELAXED,
                             __HIP_MEMORY_SCOPE_AGENT);

    // ---- out-stores (off the inter-group critical path) ----
    if (t >= 1) {
      const int tm1 = t - 1;
#pragma unroll
      for (int j = 0; j < 4; ++j) {
        int row = rb + rl + j;
        stout(out, ((size_t)tm1 * ROWS + row) * HID + d, h1p[j], f32w);
        if (tm1 == 63)
          stout(out, OUT_HID_OFF + (size_t)SLOT + (size_t)row * HID + d,
                h1p[j], f32w);
      }
    }
    if (t == 63) {
#pragma unroll
      for (int j = 0; j < 4; ++j) {
        int row = rb + rl + j;
        stout(out, OUT_HID_OFF + (size_t)row * HID + d, h0p[j], f32w);
      }
    }
  }
}

// --------------------------- host launcher ---------------------------------
extern "C" void kernel_launch(void* const* d_in, const int* in_sizes, int n_in,
                              void* d_out, int out_size, void* d_ws, size_t ws_size,
                              hipStream_t stream) {
  (void)in_sizes; (void)n_in; (void)out_size; (void)ws_size;
  const void* x   = d_in[0];
  const void* wi0 = d_in[1];
  const void* wh0 = d_in[2];
  const void* bi0 = d_in[3];
  const void* bh0 = d_in[4];
  const void* wi1 = d_in[5];
  const void* wh1 = d_in[6];
  const void* bi1 = d_in[7];
  const void* bh1 = d_in[8];
  void* out = d_out;

  char* ws = (char*)d_ws;
  unsigned* flags = (unsigned*)ws;                                  // 128 x 256 B
  unsigned* flag  = (unsigned*)(ws + 32768);                        // dtype flag
  unsigned short* ring0 = (unsigned short*)(ws + 36864);            // 2 MB
  unsigned short* ring1 = (unsigned short*)(ws + 36864 + 2097152);  // 2 MB
  unsigned short* pwi0 = (unsigned short*)(ws + 36864 + 4194304);   // 96 KB
  unsigned short* pwh0 = pwi0 + 49152;                              // 384 KB
  unsigned short* pwi1 = pwh0 + 196608;                             // 384 KB
  unsigned short* pwh1 = pwi1 + 196608;                             // 384 KB

  // zero: flags + dtype flag (rings are write-before-read under the protocol)
  hipMemsetAsync(d_ws, 0, 36864, stream);

  probe_dtype<<<1, 64, 0, stream>>>((const unsigned short*)x, flag);

  pack_w<<<(48 * 2 * 64 + 255) / 256, 256, 0, stream>>>(wi0, pwi0, 2, flag);
  pack_w<<<(48 * 8 * 64 + 255) / 256, 256, 0, stream>>>(wh0, pwh0, 8, flag);
  pack_w<<<(48 * 8 * 64 + 255) / 256, 256, 0, stream>>>(wi1, pwi1, 8, flag);
  pack_w<<<(48 * 8 * 64 + 255) / 256, 256, 0, stream>>>(wh1, pwh1, 8, flag);

  void* kargs[] = {&x, &bi0, &bh0, &bi1, &bh1, &pwi0, &pwh0, &pwi1, &pwh1,
                   &out, &ring0, &ring1, &flags, &flag};
  hipError_t lerr = hipLaunchCooperativeKernel(
      (const void*)gru_main, dim3(512), dim3(256), kargs, 0, stream);
  if (lerr != hipSuccess) {
    (void)hipGetLastError();  // clear sticky error; plain launch is safe:
    // groups are independent and members have consecutive bids -> any
    // dispatched prefix contains whole groups that complete and retire.
    gru_main<<<dim3(512), dim3(256), 0, stream>>>(
        x, bi0, bh0, bi1, bh1, pwi0, pwh0, pwi1, pwh1,
        out, ring0, ring1, flags, flag);
  }
}

// Round 10
// 703.945 us; speedup vs baseline: 2.1506x; 2.1506x over previous
//
#include <hip/hip_runtime.h>

// ---------------------------------------------------------------------------
// 2-layer GRU, H=256, seq=64, rows = B*N = 2048.
// 64 row-groups (32 rows) x 4 dim-slices (64 dims) = 256 WGs, grid 256 (1/CU).
// XCD-LOCAL GROUPS: g = bid & 63, slice = bid >> 6 -> group members at bids
// {g, g+64, g+128, g+192}, all congruent mod 8 -> SAME XCD under round-robin
// dispatch -> ring exchange stays in the local L2 (r9 showed cross-XCD
// placement costs 566 MB of MALL/HBM FETCH and 2x duration).
// Exchange is fragment-linear and line-coalesced:
//   producer: gates -> LDS h-stage (2B) -> ONE 16B coherent store per thread
//   consumer: 16B coherent loads stage ALL A-frags into LDS once per WG.
// Rings hold packed MFMA A-fragments: ring[slot][group][ff][lane][8].
// Weights stream per-wave from L2 (packed B-frag layout).
// Sync: relaxed agent-scope atomics only (coherence point), no fences.
// ---------------------------------------------------------------------------

typedef __attribute__((ext_vector_type(8))) __bf16 bf8;
typedef __attribute__((ext_vector_type(8))) unsigned short u16x8;
typedef __attribute__((ext_vector_type(4))) float f32x4;

#define MFMA16(A, B, C) __builtin_amdgcn_mfma_f32_16x16x32_bf16((A), (B), (C), 0, 0, 0)

#define ROWS 2048
#define HID 256
#define NW 768
#define SLOT (ROWS * HID)                       // 524288
#define OUT_HID_OFF ((size_t)64 * ROWS * HID)   // 33554432
#define R0SLOT 524288                           // u16 per ring slot (64 g * 8192)

static __device__ __forceinline__ float b2f(unsigned short u) {
  union { unsigned u32; float f; } v;
  v.u32 = ((unsigned)u) << 16;
  return v.f;
}
static __device__ __forceinline__ unsigned short f2b(float f) {
  unsigned u = __float_as_uint(f);
  u += 0x7fffu + ((u >> 16) & 1u);  // RNE
  return (unsigned short)(u >> 16);
}
static __device__ __forceinline__ float sigm(float x) {
  return 1.0f / (1.0f + __expf(-x));
}
static __device__ __forceinline__ float tanh_fast(float x) {
  x = fminf(15.0f, fmaxf(-15.0f, x));
  float e = __expf(2.0f * x);
  return (e - 1.0f) / (e + 1.0f);
}
static __device__ __forceinline__ float ldin(const void* p, int i, int f32w) {
  return f32w ? ((const float*)p)[i] : b2f(((const unsigned short*)p)[i]);
}
static __device__ __forceinline__ void stout(void* p, size_t i, float v, int f32w) {
  if (f32w) ((float*)p)[i] = v;
  else ((unsigned short*)p)[i] = f2b(v);
}

// Coherent 16B load / store: relaxed agent-scope u64 atomic pairs (bypass
// stale L1; served at the coherence point — local L2 when producer and
// consumer share an XCD). Compiler-tracked vmcnt.
static __device__ __forceinline__ u16x8 ld_h16(const unsigned short* p) {
  union { unsigned long long q[2]; u16x8 b; } u;
  u.q[0] = __hip_atomic_load((const unsigned long long*)p, __ATOMIC_RELAXED,
                             __HIP_MEMORY_SCOPE_AGENT);
  u.q[1] = __hip_atomic_load((const unsigned long long*)(p + 4), __ATOMIC_RELAXED,
                             __HIP_MEMORY_SCOPE_AGENT);
  return u.b;
}
static __device__ __forceinline__ void st_h16(unsigned short* p, u16x8 v) {
  union { u16x8 s; unsigned long long q[2]; } u;
  u.s = v;
  __hip_atomic_store((unsigned long long*)p, u.q[0], __ATOMIC_RELAXED,
                     __HIP_MEMORY_SCOPE_AGENT);
  __hip_atomic_store((unsigned long long*)(p + 4), u.q[1], __ATOMIC_RELAXED,
                     __HIP_MEMORY_SCOPE_AGENT);
}

// --------------------------- dtype probe -----------------------------------
__global__ void probe_dtype(const unsigned short* x, unsigned* flag) {
  if (blockIdx.x != 0 || threadIdx.x != 0) return;
  int cnt = 0;
  for (int i = 0; i < 256; ++i) {
    float v = b2f(x[i]);
    if (v == v && fabsf(v) <= 8.0f) cnt++;
  }
  *flag = (cnt >= 250) ? 0u : 1u;  // 0 = bf16 world, 1 = f32 world
}

// --------------------------- weight pre-pack -------------------------------
// packed[nb][kk][lane][e] = W[kk*32 + (lane>>4)*8 + e][nb*16 + (lane&15)]
__global__ void pack_w(const void* __restrict__ W,
                       unsigned short* __restrict__ P, int KK,
                       const unsigned* __restrict__ flag) {
  int i = blockIdx.x * blockDim.x + threadIdx.x;
  int total = 48 * KK * 64;
  if (i >= total) return;
  int f32w = (int)*flag;
  int l = i & 63;
  int kk = (i >> 6) % KK;
  int nb = i / (64 * KK);
  int n = nb * 16 + (l & 15);
  int k0 = kk * 32 + (l >> 4) * 8;
  u16x8 tmp;
#pragma unroll
  for (int e = 0; e < 8; ++e) tmp[e] = f2b(ldin(W, (k0 + e) * NW + n, f32w));
  *(u16x8*)(P + (size_t)i * 8) = tmp;
}

// --------------------------- main kernel -----------------------------------
__global__ void __launch_bounds__(256, 1) gru_main(
    const void* __restrict__ x,
    const void* __restrict__ bi0, const void* __restrict__ bh0,
    const void* __restrict__ bi1, const void* __restrict__ bh1,
    const unsigned short* __restrict__ pwi0, const unsigned short* __restrict__ pwh0,
    const unsigned short* __restrict__ pwi1, const unsigned short* __restrict__ pwh1,
    void* __restrict__ out,
    unsigned short* __restrict__ ring0, unsigned short* __restrict__ ring1,
    unsigned* __restrict__ flags, const unsigned* __restrict__ flag) {
  // LDS: A-frag stage [2 layers][16 frags][512] + h transpose stage [2][32][72]
  __shared__ __align__(16) unsigned short AS[16384];   // 32 KB
  __shared__ __align__(16) unsigned short HS[2][2304]; // 9 KB

  const int f32w = (int)*flag;
  const int tid = threadIdx.x;
  const int lane = tid & 63;
  const int wid = tid >> 6;
  const int bid = blockIdx.x;
  const int g = bid & 63;      // row group (32 rows); members stride-64 bids
  const int slice = bid >> 6;  // dim slice (64 dims) — members share an XCD
  const int nb = slice * 4 + wid;          // wave's 16-col block (0..15)

  const int d = nb * 16 + (lane & 15);     // wave's gate dim for acc col
  const int rb = g * 32;
  const int arow = rb + (lane & 15);
  const int koff = (lane >> 4) * 8;
  const int rl = (lane >> 4) * 4;
  const int cl = wid * 16 + (lane & 15);   // local col in h-stage [0,64)

  unsigned* flagp = flags + (size_t)g * 64;  // 256 B stride per group

  const unsigned short* xw  = pwi0 + (size_t)nb * 1024;  // wi0 frag base
  const unsigned short* w0  = pwh0 + (size_t)nb * 4096;  // wh0 frag base
  const unsigned short* w1i = pwi1 + (size_t)nb * 4096;  // wi1 frag base
  const unsigned short* w1h = pwh1 + (size_t)nb * 4096;  // wh1 frag base

  const float iR0 = ldin(bi0, d, f32w) + ldin(bh0, d, f32w);
  const float iZ0 = ldin(bi0, 256 + d, f32w) + ldin(bh0, 256 + d, f32w);
  const float iI0 = ldin(bi0, 512 + d, f32w);
  const float iH0 = ldin(bh0, 512 + d, f32w);
  const float iR1 = ldin(bi1, d, f32w) + ldin(bh1, d, f32w);
  const float iZ1 = ldin(bi1, 256 + d, f32w) + ldin(bh1, 256 + d, f32w);
  const float iI1 = ldin(bi1, 512 + d, f32w);
  const float iH1 = ldin(bh1, 512 + d, f32w);

  float h0p[2][4] = {{0, 0, 0, 0}, {0, 0, 0, 0}};
  float h1p[2][4] = {{0, 0, 0, 0}, {0, 0, 0, 0}};

  // emit-slot constants (one 16B ring store per thread per layer)
  const int ef = tid >> 7;              // rowfrag
  const int ekk = (tid >> 6) & 1;       // local kk within slice
  const int eln = tid & 63;
  const int ehs = (ef * 16 + (eln & 15)) * 72 + ekk * 32 + (eln >> 4) * 8;
  const size_t ero = (size_t)g * 8192 +
                     (size_t)(ef * 8 + slice * 2 + ekk) * 512 + eln * 8;

  for (int t = 0; t <= 64; ++t) {
    const int sc = t & 1;
    const int sp = sc ^ 1;

    f32x4 aR0[2], aZ0[2], aI0[2], aH0[2], aR1[2], aZ1[2], aI1[2], aH1[2];
#pragma unroll
    for (int f = 0; f < 2; ++f) {
      aR0[f] = (f32x4){iR0, iR0, iR0, iR0};
      aZ0[f] = (f32x4){iZ0, iZ0, iZ0, iZ0};
      aI0[f] = (f32x4){iI0, iI0, iI0, iI0};
      aH0[f] = (f32x4){iH0, iH0, iH0, iH0};
      aR1[f] = (f32x4){iR1, iR1, iR1, iR1};
      aZ1[f] = (f32x4){iZ1, iZ1, iZ1, iZ1};
      aI1[f] = (f32x4){iI1, iI1, iI1, iI1};
      aH1[f] = (f32x4){iH1, iH1, iH1, iH1};
    }

    // ---- x-GEMM prefetch (no group dependency) ----
    if (t < 64) {
      size_t xoff = ((size_t)t * ROWS + arow) * 64 + koff;
#pragma unroll
      for (int kk = 0; kk < 2; ++kk) {
        union { u16x8 u; bf8 b; } A0, A1;
        if (f32w) {
          const float* ab = (const float*)x + xoff;
#pragma unroll
          for (int e = 0; e < 8; ++e) {
            A0.u[e] = f2b(ab[kk * 32 + e]);
            A1.u[e] = f2b(ab[16 * 64 + kk * 32 + e]);
          }
        } else {
          const unsigned short* ab = (const unsigned short*)x + xoff;
          A0.u = *(const u16x8*)(ab + kk * 32);
          A1.u = *(const u16x8*)(ab + 16 * 64 + kk * 32);
        }
        const int lb = lane * 8;
        bf8 Br = *(const bf8*)(xw + 0 * 16384 + kk * 512 + lb);
        bf8 Bz = *(const bf8*)(xw + 1 * 16384 + kk * 512 + lb);
        bf8 Bn = *(const bf8*)(xw + 2 * 16384 + kk * 512 + lb);
        aR0[0] = MFMA16(A0.b, Br, aR0[0]);
        aR0[1] = MFMA16(A1.b, Br, aR0[1]);
        aZ0[0] = MFMA16(A0.b, Bz, aZ0[0]);
        aZ0[1] = MFMA16(A1.b, Bz, aZ0[1]);
        aI0[0] = MFMA16(A0.b, Bn, aI0[0]);
        aI0[1] = MFMA16(A1.b, Bn, aI0[1]);
      }
    }

    // ---- group barrier wait: all 4 WGs of the group finished phase t-1 ----
    if (t > 0 && tid == 0) {
      const unsigned tgt = 4u * (unsigned)t;
      while (__hip_atomic_load(flagp, __ATOMIC_RELAXED,
                               __HIP_MEMORY_SCOPE_AGENT) < tgt)
        __builtin_amdgcn_s_sleep(1);
    }
    __syncthreads();

    // ---- stage A-frags into LDS: coalesced coherent 16B loads, once/WG ----
    {
      const unsigned short* r0 = ring0 + (size_t)sp * R0SLOT + (size_t)g * 8192;
#pragma unroll
      for (int i = 0; i < 4; ++i) {
        int idx = tid + i * 256;
        int ff = idx >> 6, ln2 = idx & 63;
        *(u16x8*)(AS + ff * 512 + ln2 * 8) = ld_h16(r0 + ff * 512 + ln2 * 8);
      }
      if (t >= 2) {
        const unsigned short* r1 = ring1 + (size_t)sc * R0SLOT + (size_t)g * 8192;
#pragma unroll
        for (int i = 0; i < 4; ++i) {
          int idx = tid + i * 256;
          int ff = idx >> 6, ln2 = idx & 63;
          *(u16x8*)(AS + 8192 + ff * 512 + ln2 * 8) =
              ld_h16(r1 + ff * 512 + ln2 * 8);
        }
      }
    }
    __syncthreads();

    // ---- fused h0(t-1) MFMAs: layer0 gates (wh0) + layer1 gi (wi1) ----
#pragma unroll
    for (int kk = 0; kk < 8; ++kk) {
      const int lb = lane * 8;
      bf8 A0 = *(const bf8*)(AS + (0 * 8 + kk) * 512 + lb);
      bf8 A1 = *(const bf8*)(AS + (1 * 8 + kk) * 512 + lb);
      bf8 Br0 = *(const bf8*)(w0 + 0 * 65536 + kk * 512 + lb);
      bf8 Bz0 = *(const bf8*)(w0 + 1 * 65536 + kk * 512 + lb);
      bf8 Bn0 = *(const bf8*)(w0 + 2 * 65536 + kk * 512 + lb);
      bf8 Br1 = *(const bf8*)(w1i + 0 * 65536 + kk * 512 + lb);
      bf8 Bz1 = *(const bf8*)(w1i + 1 * 65536 + kk * 512 + lb);
      bf8 Bn1 = *(const bf8*)(w1i + 2 * 65536 + kk * 512 + lb);
      aR0[0] = MFMA16(A0, Br0, aR0[0]);
      aR0[1] = MFMA16(A1, Br0, aR0[1]);
      aZ0[0] = MFMA16(A0, Bz0, aZ0[0]);
      aZ0[1] = MFMA16(A1, Bz0, aZ0[1]);
      aH0[0] = MFMA16(A0, Bn0, aH0[0]);
      aH0[1] = MFMA16(A1, Bn0, aH0[1]);
      aR1[0] = MFMA16(A0, Br1, aR1[0]);
      aR1[1] = MFMA16(A1, Br1, aR1[1]);
      aZ1[0] = MFMA16(A0, Bz1, aZ1[0]);
      aZ1[1] = MFMA16(A1, Bz1, aZ1[1]);
      aI1[0] = MFMA16(A0, Bn1, aI1[0]);
      aI1[1] = MFMA16(A1, Bn1, aI1[1]);
    }
    // ---- h1(t-2) MFMAs: layer1 gh (wh1) ----
    if (t >= 2) {
#pragma unroll
      for (int kk = 0; kk < 8; ++kk) {
        const int lb = lane * 8;
        bf8 A0 = *(const bf8*)(AS + 8192 + (0 * 8 + kk) * 512 + lb);
        bf8 A1 = *(const bf8*)(AS + 8192 + (1 * 8 + kk) * 512 + lb);
        bf8 Br = *(const bf8*)(w1h + 0 * 65536 + kk * 512 + lb);
        bf8 Bz = *(const bf8*)(w1h + 1 * 65536 + kk * 512 + lb);
        bf8 Bn = *(const bf8*)(w1h + 2 * 65536 + kk * 512 + lb);
        aR1[0] = MFMA16(A0, Br, aR1[0]);
        aR1[1] = MFMA16(A1, Br, aR1[1]);
        aZ1[0] = MFMA16(A0, Bz, aZ1[0]);
        aZ1[1] = MFMA16(A1, Bz, aZ1[1]);
        aH1[0] = MFMA16(A0, Bn, aH1[0]);
        aH1[1] = MFMA16(A1, Bn, aH1[1]);
      }
    }

    // ---- epilogues: gate math, update reg h, write LDS h-stage (2B) ----
    if (t < 64) {
#pragma unroll
      for (int f = 0; f < 2; ++f) {
#pragma unroll
        for (int j = 0; j < 4; ++j) {
          float r = sigm(aR0[f][j]);
          float z = sigm(aZ0[f][j]);
          float n = tanh_fast(aI0[f][j] + r * aH0[f][j]);
          float hv = (1.0f - z) * n + z * h0p[f][j];
          h0p[f][j] = hv;
          HS[0][(f * 16 + rl + j) * 72 + cl] = f2b(hv);
        }
      }
    }
    if (t >= 1) {
#pragma unroll
      for (int f = 0; f < 2; ++f) {
#pragma unroll
        for (int j = 0; j < 4; ++j) {
          float r = sigm(aR1[f][j]);
          float z = sigm(aZ1[f][j]);
          float n = tanh_fast(aI1[f][j] + r * aH1[f][j]);
          float hv = (1.0f - z) * n + z * h1p[f][j];
          h1p[f][j] = hv;
          HS[1][(f * 16 + rl + j) * 72 + cl] = f2b(hv);
        }
      }
    }
    __syncthreads();

    // ---- emit: ONE coalesced 16B coherent ring store per thread/layer ----
    if (t < 64) {
      st_h16(ring0 + (size_t)sc * R0SLOT + ero, *(const u16x8*)(&HS[0][ehs]));
      if (t >= 1)
        st_h16(ring1 + (size_t)sp * R0SLOT + ero, *(const u16x8*)(&HS[1][ehs]));
    }

    // ---- arrival: drain stores, whole-WG barrier, one flag add ----
    asm volatile("s_waitcnt vmcnt(0)" ::: "memory");
    __syncthreads();
    if (t < 64 && tid == 0)
      __hip_atomic_fetch_add(flagp, 1u, __ATOMIC_RELAXED,
                             __HIP_MEMORY_SCOPE_AGENT);

    // ---- post-arrival out-stores (off the inter-group critical path) ----
    if (t >= 1) {
      const int tm1 = t - 1;
#pragma unroll
      for (int f = 0; f < 2; ++f) {
#pragma unroll
        for (int j = 0; j < 4; ++j) {
          int row = rb + f * 16 + rl + j;
          stout(out, ((size_t)tm1 * ROWS + row) * HID + d, h1p[f][j], f32w);
          if (tm1 == 63)
            stout(out, OUT_HID_OFF + (size_t)SLOT + (size_t)row * HID + d,
                  h1p[f][j], f32w);
        }
      }
    }
    if (t == 63) {
#pragma unroll
      for (int f = 0; f < 2; ++f) {
#pragma unroll
        for (int j = 0; j < 4; ++j) {
          int row = rb + f * 16 + rl + j;
          stout(out, OUT_HID_OFF + (size_t)row * HID + d, h0p[f][j], f32w);
        }
      }
    }
  }
}

// --------------------------- host launcher ---------------------------------
extern "C" void kernel_launch(void* const* d_in, const int* in_sizes, int n_in,
                              void* d_out, int out_size, void* d_ws, size_t ws_size,
                              hipStream_t stream) {
  (void)in_sizes; (void)n_in; (void)out_size; (void)ws_size;
  const void* x   = d_in[0];
  const void* wi0 = d_in[1];
  const void* wh0 = d_in[2];
  const void* bi0 = d_in[3];
  const void* bh0 = d_in[4];
  const void* wi1 = d_in[5];
  const void* wh1 = d_in[6];
  const void* bi1 = d_in[7];
  const void* bh1 = d_in[8];
  void* out = d_out;

  char* ws = (char*)d_ws;
  unsigned* flags = (unsigned*)ws;                                  // 64 x 256 B
  unsigned* flag  = (unsigned*)(ws + 16384);                        // dtype flag
  unsigned short* ring0 = (unsigned short*)(ws + 32768);            // 2 MB
  unsigned short* ring1 = (unsigned short*)(ws + 32768 + 2097152);  // 2 MB
  unsigned short* pwi0 = (unsigned short*)(ws + 32768 + 4194304);   // 96 KB
  unsigned short* pwh0 = pwi0 + 49152;                              // 384 KB
  unsigned short* pwi1 = pwh0 + 196608;                             // 384 KB
  unsigned short* pwh1 = pwi1 + 196608;                             // 384 KB

  // zero: flags + dtype flag + ring0 (h0(-1)=0). ring1 written before read.
  hipMemsetAsync(d_ws, 0, 32768 + 2097152, stream);

  probe_dtype<<<1, 64, 0, stream>>>((const unsigned short*)x, flag);

  pack_w<<<(48 * 2 * 64 + 255) / 256, 256, 0, stream>>>(wi0, pwi0, 2, flag);
  pack_w<<<(48 * 8 * 64 + 255) / 256, 256, 0, stream>>>(wh0, pwh0, 8, flag);
  pack_w<<<(48 * 8 * 64 + 255) / 256, 256, 0, stream>>>(wi1, pwi1, 8, flag);
  pack_w<<<(48 * 8 * 64 + 255) / 256, 256, 0, stream>>>(wh1, pwh1, 8, flag);

  void* kargs[] = {&x, &bi0, &bh0, &bi1, &bh1, &pwi0, &pwh0, &pwi1, &pwh1,
                   &out, &ring0, &ring1, &flags, &flag};
  hipError_t lerr = hipLaunchCooperativeKernel(
      (const void*)gru_main, dim3(256), dim3(256), kargs, 0, stream);
  if (lerr != hipSuccess) {
    (void)hipGetLastError();  // clear sticky error; plain launch is safe:
    // groups are independent; any dispatched subset makes forward progress
    // because group members never wait on WGs outside their own group.
    gru_main<<<dim3(256), dim3(256), 0, stream>>>(
        x, bi0, bh0, bi1, bh1, pwi0, pwh0, pwi1, pwh1,
        out, ring0, ring1, flags, flag);
  }
}